// Round 7
// baseline (844.414 us; speedup 1.0000x reference)
//
#include <hip/hip_runtime.h>

#define THREADS 256
#define TA 512                  // k_agg block size
#define BSH 7
#define BN  128                 // nodes per bucket
#define NBMAX 1024              // max buckets (n <= 131072)
#define NREG 8                  // src regions
#define NREG_SH 3
#define RSH 14                  // src region shift (16384 nodes ~ 1MB of 16-wide rows)
#define NBINMAX 8192            // max bins = NBMAX * NREG
#define NBLK 128                // partition blocks
#define SCAN_WG 1024
#define PAD 17                  // LDS accumulator row stride (floats)

// ---------------- pass 1: per-(bin,block) histogram ----------------
__global__ __launch_bounds__(THREADS) void k_hist(const int* __restrict__ src,
                                                  const int* __restrict__ dst,
                                                  int* __restrict__ tbl,
                                                  int E, int nbins, int chunk) {
    __shared__ int h[NBINMAX];
    for (int i = threadIdx.x; i < nbins; i += THREADS) h[i] = 0;
    __syncthreads();
    const int e0 = blockIdx.x * chunk;
    const int e1 = min(E, e0 + chunk);
    for (int e = e0 + threadIdx.x; e < e1; e += THREADS) {
        int bin = ((dst[e] >> BSH) << NREG_SH) | ((src[e] >> RSH) & (NREG - 1));
        atomicAdd(&h[bin], 1);
    }
    __syncthreads();
    for (int b = threadIdx.x; b < nbins; b += THREADS)
        tbl[b * NBLK + blockIdx.x] = h[b];          // bin-major
}

// ---------------- in-place scan of tbl (T = nbins*NBLK entries) ----------------
__global__ __launch_bounds__(SCAN_WG) void k_scanA(int* __restrict__ tbl,
                                                   int* __restrict__ bsum, int T) {
    __shared__ int s[SCAN_WG];
    const int tid = threadIdx.x;
    const int i = blockIdx.x * SCAN_WG + tid;
    int v = (i < T) ? tbl[i] : 0;
    int a = v;
    s[tid] = a; __syncthreads();
    for (int d = 1; d < SCAN_WG; d <<= 1) {
        int add = (tid >= d) ? s[tid - d] : 0;
        __syncthreads();
        a += add; s[tid] = a;
        __syncthreads();
    }
    if (i < T) tbl[i] = a - v;                      // exclusive
    if (tid == SCAN_WG - 1) bsum[blockIdx.x] = a;
}

__global__ __launch_bounds__(SCAN_WG) void k_scanB(int* __restrict__ bsum, int nbs) {
    __shared__ int s[SCAN_WG];
    const int tid = threadIdx.x;
    int v = (tid < nbs) ? bsum[tid] : 0;
    int a = v;
    s[tid] = a; __syncthreads();
    for (int d = 1; d < SCAN_WG; d <<= 1) {
        int add = (tid >= d) ? s[tid - d] : 0;
        __syncthreads();
        a += add; s[tid] = a;
        __syncthreads();
    }
    if (tid < nbs) bsum[tid] = a - v;
}

__global__ __launch_bounds__(SCAN_WG) void k_scanC(int* __restrict__ tbl,
                                                   const int* __restrict__ bsum, int T) {
    const int i = blockIdx.x * SCAN_WG + threadIdx.x;
    if (i < T) tbl[i] += bsum[blockIdx.x];
}

__global__ __launch_bounds__(THREADS) void k_bmeta(const int* __restrict__ tbl,
                                                   int* __restrict__ boff,
                                                   int* __restrict__ bcnt, int nb, int E) {
    const int b = blockIdx.x * THREADS + threadIdx.x;
    if (b < nb) {
        int s0 = tbl[((size_t)b * NREG) * NBLK];
        int s1 = (b + 1 < nb) ? tbl[((size_t)(b + 1) * NREG) * NBLK] : E;
        boff[b] = s0; bcnt[b] = s1 - s0;
    }
}

// ---------------- pass 2: private-offset fill (LDS atomics only) ----------------
__global__ __launch_bounds__(THREADS) void k_fill(const int* __restrict__ src,
                                                  const int* __restrict__ dst,
                                                  const int* __restrict__ tbl,
                                                  int* __restrict__ ebuf,
                                                  int E, int nbins, int chunk) {
    __shared__ int wp[NBINMAX];
    for (int b = threadIdx.x; b < nbins; b += THREADS)
        wp[b] = tbl[b * NBLK + blockIdx.x];
    __syncthreads();
    const int e0 = blockIdx.x * chunk;
    const int e1 = min(E, e0 + chunk);
    for (int e = e0 + threadIdx.x; e < e1; e += THREADS) {
        int s = src[e], d = dst[e];
        int bin = ((d >> BSH) << NREG_SH) | ((s >> RSH) & (NREG - 1));
        int pos = atomicAdd(&wp[bin], 1);
        ebuf[pos] = (s << BSH) | (d & (BN - 1));
    }
}

// ---------------- degree -> dinv (per-bucket LDS histogram) ----------------
__global__ __launch_bounds__(THREADS) void k_deg(const int* __restrict__ ebuf,
                                                 const int* __restrict__ boff,
                                                 const int* __restrict__ bcnt,
                                                 float* __restrict__ dinv, int n) {
    __shared__ int h[BN];
    const int b = blockIdx.x, t = threadIdx.x;
    if (t < BN) h[t] = 0;
    __syncthreads();
    const int beg = boff[b], m = bcnt[b];
    for (int j = t; j < m; j += THREADS)
        atomicAdd(&h[ebuf[beg + j] & (BN - 1)], 1);
    __syncthreads();
    if (t < BN) {
        int node = (b << BSH) + t;
        if (node < n) dinv[node] = rsqrtf((float)h[t] + 1.0f);  // +1 self loop
    }
}

// ---------------- GEMM1: xw[i][f] = (x[i] @ W1)[f] * dinv[i] ----------------
__global__ __launch_bounds__(THREADS) void k_gemm1(const float* __restrict__ x,
                                                   const float* __restrict__ W1,
                                                   const float* __restrict__ dinv,
                                                   float* __restrict__ xw, int n) {
    __shared__ float xs[16 * 292];
    __shared__ float wsh[288 * 16];
    const int t = threadIdx.x;
    const int block0 = blockIdx.x * 16;

    for (int i = t; i < 288 * 16; i += THREADS) wsh[i] = W1[i];

    int rows = n - block0; if (rows > 16) rows = 16;
    const float4* x4 = reinterpret_cast<const float4*>(x + (size_t)block0 * 288);
    const int tot4 = rows * 72;
    for (int i = t; i < tot4; i += THREADS) {
        int r = i / 72, c = i - r * 72;
        *reinterpret_cast<float4*>(&xs[r * 292 + c * 4]) = x4[i];
    }
    __syncthreads();

    const int nl = t >> 4, f = t & 15;
    const int row = block0 + nl;
    if (row < n) {
        float acc = 0.f;
        #pragma unroll 8
        for (int k = 0; k < 288; ++k)
            acc = fmaf(xs[nl * 292 + k], wsh[k * 16 + f], acc);
        xw[(size_t)row * 16 + f] = acc * dinv[row];
    }
}

// ---------------- binned LDS push aggregation, F=16, float4 gathers ----------------
// input rows pre-scaled by dinv[src]; self-loop = own row.
// EPI==1: out = relu(acc*dinv + bias[f]) * dinv   (layer-1 epilogue, pre-scaled for next agg)
// EPI==0: out = acc*dinv
template <int EPI>
__global__ __launch_bounds__(TA) void k_agg16(const float* __restrict__ xws,
                                              const int* __restrict__ ebuf,
                                              const int* __restrict__ boff,
                                              const int* __restrict__ bcnt,
                                              const float* __restrict__ dinv,
                                              const float* __restrict__ bias,
                                              float* __restrict__ out, int n) {
    __shared__ float acc[BN * PAD];
    const int b = blockIdx.x, t = threadIdx.x;
    const int base = b << BSH;

    for (int idx = t; idx < BN * 16; idx += TA) {
        int rr = idx >> 4, f = idx & 15;
        int node = base + rr;
        acc[rr * PAD + f] = (node < n) ? xws[(size_t)node * 16 + f] : 0.f;  // self
    }
    __syncthreads();

    const int beg = boff[b], m = bcnt[b];
    const int q4 = (t & 3) * 4;            // float4 quarter of the row
    constexpr int EP = TA / 4;             // entries per iteration
    #pragma unroll 4
    for (int j = t >> 2; j < m; j += EP) {
        int ent = ebuf[beg + j];
        int s = ent >> BSH, dl = ent & (BN - 1);
        float4 v = *reinterpret_cast<const float4*>(&xws[(size_t)s * 16 + q4]);
        float* a = &acc[dl * PAD + q4];
        atomicAdd(&a[0], v.x);
        atomicAdd(&a[1], v.y);
        atomicAdd(&a[2], v.z);
        atomicAdd(&a[3], v.w);
    }
    __syncthreads();

    for (int idx = t; idx < BN * 16; idx += TA) {
        int rr = idx >> 4, f = idx & 15;
        int node = base + rr;
        if (node < n) {
            float dv = dinv[node];
            float v = acc[rr * PAD + f] * dv;
            if (EPI) v = fmaxf(v + bias[f], 0.f) * dv;
            out[(size_t)node * 16 + f] = v;
        }
    }
}

// ---------------- fused head: out = relu(s2 @ W2 + b2) @ Wfc + bfc ----------------
__global__ __launch_bounds__(THREADS) void k_head(const float* __restrict__ s2,
                                                  const float* __restrict__ W2,
                                                  const float* __restrict__ b2,
                                                  const float* __restrict__ Wfc,
                                                  const float* __restrict__ bfc,
                                                  float* __restrict__ out, int n) {
    __shared__ float w2[16 * 32];
    __shared__ float wf[32 * 7];
    __shared__ float bb2[32];
    __shared__ float bbf[7];
    const int t = threadIdx.x;
    for (int i = t; i < 16 * 32; i += THREADS) w2[i] = W2[i];
    for (int i = t; i < 32 * 7; i += THREADS) wf[i] = Wfc[i];
    if (t < 32) bb2[t] = b2[t];
    if (t < 7)  bbf[t] = bfc[t];
    __syncthreads();

    const int i = blockIdx.x * THREADS + t;
    if (i >= n) return;

    float v[16];
    const float4* p = reinterpret_cast<const float4*>(s2 + (size_t)i * 16);
    #pragma unroll
    for (int q = 0; q < 4; ++q) {
        float4 x4 = p[q];
        v[q * 4 + 0] = x4.x; v[q * 4 + 1] = x4.y; v[q * 4 + 2] = x4.z; v[q * 4 + 3] = x4.w;
    }
    float h[32];
    #pragma unroll
    for (int o = 0; o < 32; ++o) {
        float a = bb2[o];
        #pragma unroll
        for (int k = 0; k < 16; ++k) a = fmaf(v[k], w2[k * 32 + o], a);
        h[o] = fmaxf(a, 0.f);
    }
    #pragma unroll
    for (int o = 0; o < 7; ++o) {
        float a = bbf[o];
        #pragma unroll
        for (int k = 0; k < 32; ++k) a = fmaf(h[k], wf[k * 7 + o], a);
        out[(size_t)i * 7 + o] = a;
    }
}

extern "C" void kernel_launch(void* const* d_in, const int* in_sizes, int n_in,
                              void* d_out, int out_size, void* d_ws, size_t ws_size,
                              hipStream_t stream) {
    const float* x   = (const float*)d_in[0];
    const int*   ei  = (const int*)d_in[1];
    const float* W1  = (const float*)d_in[2];
    const float* b1  = (const float*)d_in[3];
    const float* W2  = (const float*)d_in[4];
    const float* b2  = (const float*)d_in[5];
    const float* Wfc = (const float*)d_in[6];
    const float* bfc = (const float*)d_in[7];

    const int n = in_sizes[0] / 288;       // 100000
    const int E = in_sizes[1] / 2;         // 3200000
    const int* src = ei;
    const int* dst = ei + E;
    const int nb = (n + BN - 1) >> BSH;    // 782
    const int nbins = nb * NREG;           // 6256
    const int T  = nbins * NBLK;           // 800768
    const int chunk = (E + NBLK - 1) / NBLK;
    const int nScan = (T + SCAN_WG - 1) / SCAN_WG;   // 782 (<= 1024)

    int*   wsI  = (int*)d_ws;
    size_t p = 0;
    int*   tbl  = wsI + p;  p += (size_t)T;
    int*   bsum = wsI + p;  p += SCAN_WG;
    int*   boff = wsI + p;  p += NBMAX;
    int*   bcnt = wsI + p;  p += NBMAX;
    int*   ebuf = wsI + p;  p += ((size_t)E + 4) & ~(size_t)3;
    float* dinv = (float*)(wsI + p);  p += ((size_t)n + 4) & ~(size_t)3;
    float* buf1 = (float*)(wsI + p);  p += (size_t)n * 16;   // xw / s2
    float* buf2 = (float*)(wsI + p);                          // t1
    float* out  = (float*)d_out;

    k_hist <<<NBLK, THREADS, 0, stream>>>(src, dst, tbl, E, nbins, chunk);
    k_scanA<<<nScan, SCAN_WG, 0, stream>>>(tbl, bsum, T);
    k_scanB<<<1, SCAN_WG, 0, stream>>>(bsum, nScan);
    k_scanC<<<nScan, SCAN_WG, 0, stream>>>(tbl, bsum, T);
    k_bmeta<<<(nb + THREADS - 1) / THREADS, THREADS, 0, stream>>>(tbl, boff, bcnt, nb, E);
    k_fill <<<NBLK, THREADS, 0, stream>>>(src, dst, tbl, ebuf, E, nbins, chunk);

    k_deg  <<<nb, THREADS, 0, stream>>>(ebuf, boff, bcnt, dinv, n);

    k_gemm1<<<(n + 15) / 16, THREADS, 0, stream>>>(x, W1, dinv, buf1, n);

    // layer-1 aggregation + fused relu/bias epilogue (pre-scaled for layer 2)
    k_agg16<1><<<nb, TA, 0, stream>>>(buf1, ebuf, boff, bcnt, dinv, b1, buf2, n);

    // layer-2 aggregation on 16-wide h1 (aggregate-before-transform)
    k_agg16<0><<<nb, TA, 0, stream>>>(buf2, ebuf, boff, bcnt, dinv, nullptr, buf1, n);

    // fused: relu(s2 @ W2 + b2) @ Wfc + bfc
    k_head <<<(n + THREADS - 1) / THREADS, THREADS, 0, stream>>>(
        buf1, W2, b2, Wfc, bfc, out, n);
}

// Round 8
// 274.133 us; speedup vs baseline: 3.0803x; 3.0803x over previous
//
#include <hip/hip_runtime.h>

#define THREADS 256
#define BSH 7
#define BN  128                 // nodes per bucket
#define NBMAX 1024              // max buckets (n <= 131072)
#define NBLK 128                // partition blocks
#define SCAN_WG 1024

// ---------------- pass 1: per-(bucket,block) histogram ----------------
__global__ __launch_bounds__(THREADS) void k_hist(const int* __restrict__ dst,
                                                  int* __restrict__ tbl,
                                                  int E, int nb, int chunk) {
    __shared__ int h[NBMAX];
    for (int i = threadIdx.x; i < nb; i += THREADS) h[i] = 0;
    __syncthreads();
    const int e0 = blockIdx.x * chunk;
    const int e1 = min(E, e0 + chunk);
    for (int e = e0 + threadIdx.x; e < e1; e += THREADS)
        atomicAdd(&h[dst[e] >> BSH], 1);
    __syncthreads();
    for (int b = threadIdx.x; b < nb; b += THREADS)
        tbl[b * NBLK + blockIdx.x] = h[b];          // bucket-major
}

// ---------------- in-place scan of tbl ----------------
__global__ __launch_bounds__(SCAN_WG) void k_scanA(int* __restrict__ tbl,
                                                   int* __restrict__ bsum, int T) {
    __shared__ int s[SCAN_WG];
    const int tid = threadIdx.x;
    const int i = blockIdx.x * SCAN_WG + tid;
    int v = (i < T) ? tbl[i] : 0;
    int a = v;
    s[tid] = a; __syncthreads();
    for (int d = 1; d < SCAN_WG; d <<= 1) {
        int add = (tid >= d) ? s[tid - d] : 0;
        __syncthreads();
        a += add; s[tid] = a;
        __syncthreads();
    }
    if (i < T) tbl[i] = a - v;                      // exclusive
    if (tid == SCAN_WG - 1) bsum[blockIdx.x] = a;
}

__global__ __launch_bounds__(SCAN_WG) void k_scanB(int* __restrict__ bsum, int nbs) {
    __shared__ int s[SCAN_WG];
    const int tid = threadIdx.x;
    int v = (tid < nbs) ? bsum[tid] : 0;
    int a = v;
    s[tid] = a; __syncthreads();
    for (int d = 1; d < SCAN_WG; d <<= 1) {
        int add = (tid >= d) ? s[tid - d] : 0;
        __syncthreads();
        a += add; s[tid] = a;
        __syncthreads();
    }
    if (tid < nbs) bsum[tid] = a - v;
}

__global__ __launch_bounds__(SCAN_WG) void k_scanC(int* __restrict__ tbl,
                                                   const int* __restrict__ bsum, int T) {
    const int i = blockIdx.x * SCAN_WG + threadIdx.x;
    if (i < T) tbl[i] += bsum[blockIdx.x];
}

__global__ __launch_bounds__(THREADS) void k_bmeta(const int* __restrict__ tbl,
                                                   int* __restrict__ boff,
                                                   int* __restrict__ bcnt, int nb, int E) {
    const int b = blockIdx.x * THREADS + threadIdx.x;
    if (b < nb) {
        int s0 = tbl[(size_t)b * NBLK];
        int s1 = (b + 1 < nb) ? tbl[(size_t)(b + 1) * NBLK] : E;
        boff[b] = s0; bcnt[b] = s1 - s0;
    }
}

// ---------------- pass 2: private-offset fill (LDS atomics only) ----------------
__global__ __launch_bounds__(THREADS) void k_fill(const int* __restrict__ src,
                                                  const int* __restrict__ dst,
                                                  const int* __restrict__ tbl,
                                                  int* __restrict__ ebuf,
                                                  int E, int nb, int chunk) {
    __shared__ int wp[NBMAX];
    for (int b = threadIdx.x; b < nb; b += THREADS)
        wp[b] = tbl[b * NBLK + blockIdx.x];
    __syncthreads();
    const int e0 = blockIdx.x * chunk;
    const int e1 = min(E, e0 + chunk);
    for (int e = e0 + threadIdx.x; e < e1; e += THREADS) {
        int s = src[e], d = dst[e];
        int pos = atomicAdd(&wp[d >> BSH], 1);
        ebuf[pos] = (s << BSH) | (d & (BN - 1));
    }
}

// ---------------- bucket -> node-sorted CSR + noff + dinv ----------------
// One block per bucket: LDS 128-bin hist, scan, scatter src ids to csr
// (writes confined to this bucket's ~16KB csr window).
__global__ __launch_bounds__(THREADS) void k_nodesort(const int* __restrict__ ebuf,
                                                      const int* __restrict__ boff,
                                                      const int* __restrict__ bcnt,
                                                      int* __restrict__ csr,
                                                      int* __restrict__ noff,
                                                      float* __restrict__ dinv, int n) {
    __shared__ int hist[BN];
    __shared__ int sc[BN];
    __shared__ int wp[BN];
    const int b = blockIdx.x, t = threadIdx.x;
    const int base = b << BSH;
    const int beg = boff[b], m = bcnt[b];

    if (t < BN) hist[t] = 0;
    __syncthreads();
    for (int j = t; j < m; j += THREADS)
        atomicAdd(&hist[ebuf[beg + j] & (BN - 1)], 1);
    __syncthreads();

    // exclusive scan over 128 bins (Hillis-Steele on first 128 threads)
    if (t < BN) sc[t] = hist[t];
    __syncthreads();
    for (int d = 1; d < BN; d <<= 1) {
        int add = 0;
        if (t < BN && t >= d) add = sc[t - d];
        __syncthreads();
        if (t < BN) sc[t] += add;
        __syncthreads();
    }
    if (t < BN) {
        int excl = sc[t] - hist[t];
        wp[t] = excl;
        int node = base + t;
        if (node <= n) noff[node] = beg + excl;     // node==n -> noff[n]=E (last bucket)
        if (node < n)  dinv[node] = rsqrtf((float)hist[t] + 1.0f);  // +1 self loop
    }
    __syncthreads();

    for (int j = t; j < m; j += THREADS) {
        int ent = ebuf[beg + j];
        int pos = atomicAdd(&wp[ent & (BN - 1)], 1);
        csr[beg + pos] = ent >> BSH;
    }
}

// ---------------- GEMM1: xw[i][f] = (x[i] @ W1)[f] * dinv[i] ----------------
__global__ __launch_bounds__(THREADS) void k_gemm1(const float* __restrict__ x,
                                                   const float* __restrict__ W1,
                                                   const float* __restrict__ dinv,
                                                   float* __restrict__ xw, int n) {
    __shared__ float xs[16 * 292];
    __shared__ float wsh[288 * 16];
    const int t = threadIdx.x;
    const int block0 = blockIdx.x * 16;

    for (int i = t; i < 288 * 16; i += THREADS) wsh[i] = W1[i];

    int rows = n - block0; if (rows > 16) rows = 16;
    const float4* x4 = reinterpret_cast<const float4*>(x + (size_t)block0 * 288);
    const int tot4 = rows * 72;
    for (int i = t; i < tot4; i += THREADS) {
        int r = i / 72, c = i - r * 72;
        *reinterpret_cast<float4*>(&xs[r * 292 + c * 4]) = x4[i];
    }
    __syncthreads();

    const int nl = t >> 4, f = t & 15;
    const int row = block0 + nl;
    if (row < n) {
        float acc = 0.f;
        #pragma unroll 8
        for (int k = 0; k < 288; ++k)
            acc = fmaf(xs[nl * 292 + k], wsh[k * 16 + f], acc);
        xw[(size_t)row * 16 + f] = acc * dinv[row];
    }
}

// ---------------- pull aggregation, F=16, register accumulate ----------------
// 4 lanes per node, each owns one float4 of the row. Input rows pre-scaled
// by dinv[src]; self-loop = own row; epilogue applies dinv[node].
// EPI==1: out = relu(acc*dinv + bias) * dinv   (layer-1, pre-scaled for layer 2)
// EPI==0: out = acc*dinv
template <int EPI>
__global__ __launch_bounds__(THREADS) void k_pull16(const float* __restrict__ xws,
                                                    const int* __restrict__ csr,
                                                    const int* __restrict__ noff,
                                                    const float* __restrict__ dinv,
                                                    const float* __restrict__ bias,
                                                    float* __restrict__ out, int n) {
    const int t = blockIdx.x * THREADS + threadIdx.x;
    const int node = t >> 2, q = t & 3;
    if (node >= n) return;
    const float4* x4 = reinterpret_cast<const float4*>(xws);
    float4 acc = x4[(size_t)node * 4 + q];          // self loop
    const int beg = noff[node], end = noff[node + 1];
    #pragma unroll 4
    for (int j = beg; j < end; ++j) {
        int s = csr[j];
        float4 v = x4[(size_t)s * 4 + q];
        acc.x += v.x; acc.y += v.y; acc.z += v.z; acc.w += v.w;
    }
    const float dv = dinv[node];
    if (EPI) {
        float4 bb = reinterpret_cast<const float4*>(bias)[q];
        acc.x = fmaxf(fmaf(acc.x, dv, bb.x), 0.f) * dv;
        acc.y = fmaxf(fmaf(acc.y, dv, bb.y), 0.f) * dv;
        acc.z = fmaxf(fmaf(acc.z, dv, bb.z), 0.f) * dv;
        acc.w = fmaxf(fmaf(acc.w, dv, bb.w), 0.f) * dv;
    } else {
        acc.x *= dv; acc.y *= dv; acc.z *= dv; acc.w *= dv;
    }
    reinterpret_cast<float4*>(out)[(size_t)node * 4 + q] = acc;
}

// ---------------- fused head: out = relu(s2 @ W2 + b2) @ Wfc + bfc ----------------
__global__ __launch_bounds__(THREADS) void k_head(const float* __restrict__ s2,
                                                  const float* __restrict__ W2,
                                                  const float* __restrict__ b2,
                                                  const float* __restrict__ Wfc,
                                                  const float* __restrict__ bfc,
                                                  float* __restrict__ out, int n) {
    __shared__ float w2[16 * 32];
    __shared__ float wf[32 * 7];
    __shared__ float bb2[32];
    __shared__ float bbf[7];
    const int t = threadIdx.x;
    for (int i = t; i < 16 * 32; i += THREADS) w2[i] = W2[i];
    for (int i = t; i < 32 * 7; i += THREADS) wf[i] = Wfc[i];
    if (t < 32) bb2[t] = b2[t];
    if (t < 7)  bbf[t] = bfc[t];
    __syncthreads();

    const int i = blockIdx.x * THREADS + t;
    if (i >= n) return;

    float v[16];
    const float4* p = reinterpret_cast<const float4*>(s2 + (size_t)i * 16);
    #pragma unroll
    for (int q = 0; q < 4; ++q) {
        float4 x4 = p[q];
        v[q * 4 + 0] = x4.x; v[q * 4 + 1] = x4.y; v[q * 4 + 2] = x4.z; v[q * 4 + 3] = x4.w;
    }
    float h[32];
    #pragma unroll
    for (int o = 0; o < 32; ++o) {
        float a = bb2[o];
        #pragma unroll
        for (int k = 0; k < 16; ++k) a = fmaf(v[k], w2[k * 32 + o], a);
        h[o] = fmaxf(a, 0.f);
    }
    #pragma unroll
    for (int o = 0; o < 7; ++o) {
        float a = bbf[o];
        #pragma unroll
        for (int k = 0; k < 32; ++k) a = fmaf(h[k], wf[k * 7 + o], a);
        out[(size_t)i * 7 + o] = a;
    }
}

extern "C" void kernel_launch(void* const* d_in, const int* in_sizes, int n_in,
                              void* d_out, int out_size, void* d_ws, size_t ws_size,
                              hipStream_t stream) {
    const float* x   = (const float*)d_in[0];
    const int*   ei  = (const int*)d_in[1];
    const float* W1  = (const float*)d_in[2];
    const float* b1  = (const float*)d_in[3];
    const float* W2  = (const float*)d_in[4];
    const float* b2  = (const float*)d_in[5];
    const float* Wfc = (const float*)d_in[6];
    const float* bfc = (const float*)d_in[7];

    const int n = in_sizes[0] / 288;       // 100000
    const int E = in_sizes[1] / 2;         // 3200000
    const int* src = ei;
    const int* dst = ei + E;
    const int nb = (n + BN - 1) >> BSH;    // 782
    const int T  = nb * NBLK;              // 100096
    const int chunk = (E + NBLK - 1) / NBLK;
    const int nScan = (T + SCAN_WG - 1) / SCAN_WG;   // 98

    int*   wsI  = (int*)d_ws;
    size_t p = 0;
    int*   tbl  = wsI + p;  p += ((size_t)T + 4) & ~(size_t)3;
    int*   bsum = wsI + p;  p += SCAN_WG;
    int*   boff = wsI + p;  p += NBMAX;
    int*   bcnt = wsI + p;  p += NBMAX;
    int*   ebuf = wsI + p;  p += ((size_t)E + 4) & ~(size_t)3;
    int*   csr  = wsI + p;  p += ((size_t)E + 4) & ~(size_t)3;
    int*   noff = wsI + p;  p += ((size_t)n + 8) & ~(size_t)3;
    float* dinv = (float*)(wsI + p);  p += ((size_t)n + 4) & ~(size_t)3;
    float* buf1 = (float*)(wsI + p);  p += (size_t)n * 16;   // xw / s2
    float* buf2 = (float*)(wsI + p);                          // h1
    float* out  = (float*)d_out;

    k_hist <<<NBLK, THREADS, 0, stream>>>(dst, tbl, E, nb, chunk);
    k_scanA<<<nScan, SCAN_WG, 0, stream>>>(tbl, bsum, T);
    k_scanB<<<1, SCAN_WG, 0, stream>>>(bsum, nScan);
    k_scanC<<<nScan, SCAN_WG, 0, stream>>>(tbl, bsum, T);
    k_bmeta<<<(nb + THREADS - 1) / THREADS, THREADS, 0, stream>>>(tbl, boff, bcnt, nb, E);
    k_fill <<<NBLK, THREADS, 0, stream>>>(src, dst, tbl, ebuf, E, nb, chunk);

    k_nodesort<<<nb, THREADS, 0, stream>>>(ebuf, boff, bcnt, csr, noff, dinv, n);

    k_gemm1<<<(n + 15) / 16, THREADS, 0, stream>>>(x, W1, dinv, buf1, n);

    // layer-1 aggregation + fused relu/bias epilogue (pre-scaled for layer 2)
    k_pull16<1><<<((size_t)n * 4 + THREADS - 1) / THREADS, THREADS, 0, stream>>>(
        buf1, csr, noff, dinv, b1, buf2, n);

    // layer-2 aggregation on 16-wide h1 (aggregate-before-transform)
    k_pull16<0><<<((size_t)n * 4 + THREADS - 1) / THREADS, THREADS, 0, stream>>>(
        buf2, csr, noff, dinv, nullptr, buf1, n);

    // fused: relu(s2 @ W2 + b2) @ Wfc + bfc
    k_head <<<(n + THREADS - 1) / THREADS, THREADS, 0, stream>>>(
        buf1, W2, b2, Wfc, bfc, out, n);
}

// Round 10
// 252.818 us; speedup vs baseline: 3.3400x; 1.0843x over previous
//
#include <hip/hip_runtime.h>

#define THREADS 256
#define BSH 7
#define BN  128                 // nodes per bucket
#define NBMAX 1024              // max buckets (n <= 131072)
#define NBLK 512                // partition blocks
#define SCAN_WG 1024
#define GN 32                   // gemm1 nodes per block
#define GT 512                  // gemm1 threads per block

// ---------------- pass 1: per-(bucket,block) histogram ----------------
__global__ __launch_bounds__(THREADS) void k_hist(const int* __restrict__ dst,
                                                  int* __restrict__ tbl,
                                                  int E, int nb, int chunk) {
    __shared__ int h[NBMAX];
    for (int i = threadIdx.x; i < nb; i += THREADS) h[i] = 0;
    __syncthreads();
    const int e0 = blockIdx.x * chunk;
    const int e1 = min(E, e0 + chunk);
    for (int e = e0 + threadIdx.x; e < e1; e += THREADS)
        atomicAdd(&h[dst[e] >> BSH], 1);
    __syncthreads();
    for (int b = threadIdx.x; b < nb; b += THREADS)
        tbl[b * NBLK + blockIdx.x] = h[b];          // bucket-major
}

// ---------------- in-place scan of tbl ----------------
__global__ __launch_bounds__(SCAN_WG) void k_scanA(int* __restrict__ tbl,
                                                   int* __restrict__ bsum, int T) {
    __shared__ int s[SCAN_WG];
    const int tid = threadIdx.x;
    const int i = blockIdx.x * SCAN_WG + tid;
    int v = (i < T) ? tbl[i] : 0;
    int a = v;
    s[tid] = a; __syncthreads();
    for (int d = 1; d < SCAN_WG; d <<= 1) {
        int add = (tid >= d) ? s[tid - d] : 0;
        __syncthreads();
        a += add; s[tid] = a;
        __syncthreads();
    }
    if (i < T) tbl[i] = a - v;                      // exclusive
    if (tid == SCAN_WG - 1) bsum[blockIdx.x] = a;
}

__global__ __launch_bounds__(SCAN_WG) void k_scanB(int* __restrict__ bsum, int nbs) {
    __shared__ int s[SCAN_WG];
    const int tid = threadIdx.x;
    int v = (tid < nbs) ? bsum[tid] : 0;
    int a = v;
    s[tid] = a; __syncthreads();
    for (int d = 1; d < SCAN_WG; d <<= 1) {
        int add = (tid >= d) ? s[tid - d] : 0;
        __syncthreads();
        a += add; s[tid] = a;
        __syncthreads();
    }
    if (tid < nbs) bsum[tid] = a - v;
}

__global__ __launch_bounds__(SCAN_WG) void k_scanC(int* __restrict__ tbl,
                                                   const int* __restrict__ bsum, int T) {
    const int i = blockIdx.x * SCAN_WG + threadIdx.x;
    if (i < T) tbl[i] += bsum[blockIdx.x];
}

__global__ __launch_bounds__(THREADS) void k_bmeta(const int* __restrict__ tbl,
                                                   int* __restrict__ boff,
                                                   int* __restrict__ bcnt, int nb, int E) {
    const int b = blockIdx.x * THREADS + threadIdx.x;
    if (b < nb) {
        int s0 = tbl[(size_t)b * NBLK];
        int s1 = (b + 1 < nb) ? tbl[(size_t)(b + 1) * NBLK] : E;
        boff[b] = s0; bcnt[b] = s1 - s0;
    }
}

// ---------------- pass 2: private-offset fill (LDS atomics only) ----------------
__global__ __launch_bounds__(THREADS) void k_fill(const int* __restrict__ src,
                                                  const int* __restrict__ dst,
                                                  const int* __restrict__ tbl,
                                                  int* __restrict__ ebuf,
                                                  int E, int nb, int chunk) {
    __shared__ int wp[NBMAX];
    for (int b = threadIdx.x; b < nb; b += THREADS)
        wp[b] = tbl[b * NBLK + blockIdx.x];
    __syncthreads();
    const int e0 = blockIdx.x * chunk;
    const int e1 = min(E, e0 + chunk);
    for (int e = e0 + threadIdx.x; e < e1; e += THREADS) {
        int s = src[e], d = dst[e];
        int pos = atomicAdd(&wp[d >> BSH], 1);
        ebuf[pos] = (s << BSH) | (d & (BN - 1));
    }
}

// ---------------- bucket -> node-sorted CSR + noff + dinv ----------------
__global__ __launch_bounds__(THREADS) void k_nodesort(const int* __restrict__ ebuf,
                                                      const int* __restrict__ boff,
                                                      const int* __restrict__ bcnt,
                                                      int* __restrict__ csr,
                                                      int* __restrict__ noff,
                                                      float* __restrict__ dinv, int n) {
    __shared__ int hist[BN];
    __shared__ int sc[BN];
    __shared__ int wp[BN];
    const int b = blockIdx.x, t = threadIdx.x;
    const int base = b << BSH;
    const int beg = boff[b], m = bcnt[b];

    if (t < BN) hist[t] = 0;
    __syncthreads();
    for (int j = t; j < m; j += THREADS)
        atomicAdd(&hist[ebuf[beg + j] & (BN - 1)], 1);
    __syncthreads();

    if (t < BN) sc[t] = hist[t];
    __syncthreads();
    for (int d = 1; d < BN; d <<= 1) {
        int add = 0;
        if (t < BN && t >= d) add = sc[t - d];
        __syncthreads();
        if (t < BN) sc[t] += add;
        __syncthreads();
    }
    if (t < BN) {
        int excl = sc[t] - hist[t];
        wp[t] = excl;
        int node = base + t;
        if (node <= n) noff[node] = beg + excl;     // node==n -> noff[n]=E (last bucket)
        if (node < n)  dinv[node] = rsqrtf((float)hist[t] + 1.0f);  // +1 self loop
    }
    __syncthreads();

    for (int j = t; j < m; j += THREADS) {
        int ent = ebuf[beg + j];
        int pos = atomicAdd(&wp[ent & (BN - 1)], 1);
        csr[beg + pos] = ent >> BSH;
    }
}

// ---------------- GEMM1: xw[i][f] = (x[i] @ W1)[f] * dinv[i] ----------------
// 32 nodes/block, 512 threads = 32 nodes x 16 feats.
// Both LDS operands read as float4 (2-way bank alias only, free).
__global__ __launch_bounds__(GT) void k_gemm1(const float* __restrict__ x,
                                              const float* __restrict__ W1,
                                              const float* __restrict__ dinv,
                                              float* __restrict__ xw, int n) {
    __shared__ float xs[GN * 292];
    __shared__ float wt[16 * 292];          // wt[f][k], transposed W1
    const int t = threadIdx.x;
    const int block0 = blockIdx.x * GN;

    for (int i = t; i < 288 * 16; i += GT) {
        int k = i >> 4, f = i & 15;
        wt[f * 292 + k] = W1[i];            // W1[k*16+f]
    }

    int rows = n - block0; if (rows > GN) rows = GN;
    const float4* x4 = reinterpret_cast<const float4*>(x + (size_t)block0 * 288);
    const int tot4 = rows * 72;             // 288/4 float4 per row
    for (int i = t; i < tot4; i += GT) {
        int r = i / 72, c = i - r * 72;
        *reinterpret_cast<float4*>(&xs[r * 292 + c * 4]) = x4[i];
    }
    __syncthreads();

    const int nl = t >> 4, f = t & 15;
    const int row = block0 + nl;
    if (row < n) {
        const float4* xr = reinterpret_cast<const float4*>(&xs[nl * 292]);
        const float4* wr = reinterpret_cast<const float4*>(&wt[f * 292]);
        float4 a4 = {0.f, 0.f, 0.f, 0.f};
        #pragma unroll 8
        for (int j = 0; j < 72; ++j) {
            float4 a = xr[j], w = wr[j];
            a4.x = fmaf(a.x, w.x, a4.x);
            a4.y = fmaf(a.y, w.y, a4.y);
            a4.z = fmaf(a.z, w.z, a4.z);
            a4.w = fmaf(a.w, w.w, a4.w);
        }
        float acc = (a4.x + a4.y) + (a4.z + a4.w);
        xw[(size_t)row * 16 + f] = acc * dinv[row];
    }
}

// ---------------- pull aggregation, F=16, register accumulate ----------------
// 4 lanes per node, each owns one float4 of the row. Input rows pre-scaled
// by dinv[src]; self-loop = own row; epilogue applies dinv[node].
template <int EPI>
__global__ __launch_bounds__(THREADS) void k_pull16(const float* __restrict__ xws,
                                                    const int* __restrict__ csr,
                                                    const int* __restrict__ noff,
                                                    const float* __restrict__ dinv,
                                                    const float* __restrict__ bias,
                                                    float* __restrict__ out, int n) {
    const int t = blockIdx.x * THREADS + threadIdx.x;
    const int node = t >> 2, q = t & 3;
    if (node >= n) return;
    const float4* x4 = reinterpret_cast<const float4*>(xws);
    float4 acc = x4[(size_t)node * 4 + q];          // self loop
    const int beg = noff[node], end = noff[node + 1];
    #pragma unroll 4
    for (int j = beg; j < end; ++j) {
        int s = csr[j];
        float4 v = x4[(size_t)s * 4 + q];
        acc.x += v.x; acc.y += v.y; acc.z += v.z; acc.w += v.w;
    }
    const float dv = dinv[node];
    if (EPI) {
        float4 bb = reinterpret_cast<const float4*>(bias)[q];
        acc.x = fmaxf(fmaf(acc.x, dv, bb.x), 0.f) * dv;
        acc.y = fmaxf(fmaf(acc.y, dv, bb.y), 0.f) * dv;
        acc.z = fmaxf(fmaf(acc.z, dv, bb.z), 0.f) * dv;
        acc.w = fmaxf(fmaf(acc.w, dv, bb.w), 0.f) * dv;
    } else {
        acc.x *= dv; acc.y *= dv; acc.z *= dv; acc.w *= dv;
    }
    reinterpret_cast<float4*>(out)[(size_t)node * 4 + q] = acc;
}

// ---------------- fused head: out = relu(s2 @ W2 + b2) @ Wfc + bfc ----------------
__global__ __launch_bounds__(THREADS) void k_head(const float* __restrict__ s2,
                                                  const float* __restrict__ W2,
                                                  const float* __restrict__ b2,
                                                  const float* __restrict__ Wfc,
                                                  const float* __restrict__ bfc,
                                                  float* __restrict__ out, int n) {
    __shared__ float w2[16 * 32];
    __shared__ float wf[32 * 7];
    __shared__ float bb2[32];
    __shared__ float bbf[7];
    const int t = threadIdx.x;
    for (int i = t; i < 16 * 32; i += THREADS) w2[i] = W2[i];
    for (int i = t; i < 32 * 7; i += THREADS) wf[i] = Wfc[i];
    if (t < 32) bb2[t] = b2[t];
    if (t < 7)  bbf[t] = bfc[t];
    __syncthreads();

    const int i = blockIdx.x * THREADS + t;
    if (i >= n) return;

    float v[16];
    const float4* p = reinterpret_cast<const float4*>(s2 + (size_t)i * 16);
    #pragma unroll
    for (int q = 0; q < 4; ++q) {
        float4 x4 = p[q];
        v[q * 4 + 0] = x4.x; v[q * 4 + 1] = x4.y; v[q * 4 + 2] = x4.z; v[q * 4 + 3] = x4.w;
    }
    float h[32];
    #pragma unroll
    for (int o = 0; o < 32; ++o) {
        float a = bb2[o];
        #pragma unroll
        for (int k = 0; k < 16; ++k) a = fmaf(v[k], w2[k * 32 + o], a);
        h[o] = fmaxf(a, 0.f);
    }
    #pragma unroll
    for (int o = 0; o < 7; ++o) {
        float a = bbf[o];
        #pragma unroll
        for (int k = 0; k < 32; ++k) a = fmaf(h[k], wf[k * 7 + o], a);
        out[(size_t)i * 7 + o] = a;
    }
}

extern "C" void kernel_launch(void* const* d_in, const int* in_sizes, int n_in,
                              void* d_out, int out_size, void* d_ws, size_t ws_size,
                              hipStream_t stream) {
    const float* x   = (const float*)d_in[0];
    const int*   ei  = (const int*)d_in[1];
    const float* W1  = (const float*)d_in[2];
    const float* b1  = (const float*)d_in[3];
    const float* W2  = (const float*)d_in[4];
    const float* b2  = (const float*)d_in[5];
    const float* Wfc = (const float*)d_in[6];
    const float* bfc = (const float*)d_in[7];

    const int n = in_sizes[0] / 288;       // 100000
    const int E = in_sizes[1] / 2;         // 3200000
    const int* src = ei;
    const int* dst = ei + E;
    const int nb = (n + BN - 1) >> BSH;    // 782
    const int T  = nb * NBLK;              // 400384
    const int chunk = (E + NBLK - 1) / NBLK;
    const int nScan = (T + SCAN_WG - 1) / SCAN_WG;   // 391

    int*   wsI  = (int*)d_ws;
    size_t p = 0;
    int*   tbl  = wsI + p;  p += ((size_t)T + 4) & ~(size_t)3;
    int*   bsum = wsI + p;  p += SCAN_WG;
    int*   boff = wsI + p;  p += NBMAX;
    int*   bcnt = wsI + p;  p += NBMAX;
    int*   ebuf = wsI + p;  p += ((size_t)E + 4) & ~(size_t)3;
    int*   csr  = wsI + p;  p += ((size_t)E + 4) & ~(size_t)3;
    int*   noff = wsI + p;  p += ((size_t)n + 8) & ~(size_t)3;
    float* dinv = (float*)(wsI + p);  p += ((size_t)n + 4) & ~(size_t)3;
    float* buf1 = (float*)(wsI + p);  p += (size_t)n * 16;   // xw / s2
    float* buf2 = (float*)(wsI + p);                          // h1
    float* out  = (float*)d_out;

    k_hist <<<NBLK, THREADS, 0, stream>>>(dst, tbl, E, nb, chunk);
    k_scanA<<<nScan, SCAN_WG, 0, stream>>>(tbl, bsum, T);
    k_scanB<<<1, SCAN_WG, 0, stream>>>(bsum, nScan);
    k_scanC<<<nScan, SCAN_WG, 0, stream>>>(tbl, bsum, T);
    k_bmeta<<<(nb + THREADS - 1) / THREADS, THREADS, 0, stream>>>(tbl, boff, bcnt, nb, E);
    k_fill <<<NBLK, THREADS, 0, stream>>>(src, dst, tbl, ebuf, E, nb, chunk);

    k_nodesort<<<nb, THREADS, 0, stream>>>(ebuf, boff, bcnt, csr, noff, dinv, n);

    k_gemm1<<<(n + GN - 1) / GN, GT, 0, stream>>>(x, W1, dinv, buf1, n);

    // layer-1 aggregation + fused relu/bias epilogue (pre-scaled for layer 2)
    k_pull16<1><<<((size_t)n * 4 + THREADS - 1) / THREADS, THREADS, 0, stream>>>(
        buf1, csr, noff, dinv, b1, buf2, n);

    // layer-2 aggregation on 16-wide h1 (aggregate-before-transform)
    k_pull16<0><<<((size_t)n * 4 + THREADS - 1) / THREADS, THREADS, 0, stream>>>(
        buf2, csr, noff, dinv, nullptr, buf1, n);

    // fused: relu(s2 @ W2 + b2) @ Wfc + bfc
    k_head <<<(n + THREADS - 1) / THREADS, THREADS, 0, stream>>>(
        buf1, W2, b2, Wfc, bfc, out, n);
}

// Round 12
// 244.791 us; speedup vs baseline: 3.4495x; 1.0328x over previous
//
#include <hip/hip_runtime.h>

#define THREADS 256
#define BSH 7
#define BN  128                 // nodes per bucket
#define NBMAX 1024              // max buckets (n <= 131072)
#define NBLK 512                // partition blocks
#define SCAN_WG 1024
#define G1_T 256                // gemm1 threads
#define G1_N 256                // gemm1 nodes per block
#define G1_KS 32                // gemm1 k-slab (288 = 9 x 32)

// ---------------- pass 1: per-(bucket,block) histogram ----------------
__global__ __launch_bounds__(THREADS) void k_hist(const int* __restrict__ dst,
                                                  int* __restrict__ tbl,
                                                  int E, int nb, int chunk) {
    __shared__ int h[NBMAX];
    for (int i = threadIdx.x; i < nb; i += THREADS) h[i] = 0;
    __syncthreads();
    const int e0 = blockIdx.x * chunk;
    const int e1 = min(E, e0 + chunk);
    for (int e = e0 + threadIdx.x; e < e1; e += THREADS)
        atomicAdd(&h[dst[e] >> BSH], 1);
    __syncthreads();
    for (int b = threadIdx.x; b < nb; b += THREADS)
        tbl[b * NBLK + blockIdx.x] = h[b];          // bucket-major
}

// ---------------- in-place scan of tbl ----------------
__global__ __launch_bounds__(SCAN_WG) void k_scanA(int* __restrict__ tbl,
                                                   int* __restrict__ bsum, int T) {
    __shared__ int s[SCAN_WG];
    const int tid = threadIdx.x;
    const int i = blockIdx.x * SCAN_WG + tid;
    int v = (i < T) ? tbl[i] : 0;
    int a = v;
    s[tid] = a; __syncthreads();
    for (int d = 1; d < SCAN_WG; d <<= 1) {
        int add = (tid >= d) ? s[tid - d] : 0;
        __syncthreads();
        a += add; s[tid] = a;
        __syncthreads();
    }
    if (i < T) tbl[i] = a - v;                      // exclusive
    if (tid == SCAN_WG - 1) bsum[blockIdx.x] = a;
}

__global__ __launch_bounds__(SCAN_WG) void k_scanB(int* __restrict__ bsum, int nbs) {
    __shared__ int s[SCAN_WG];
    const int tid = threadIdx.x;
    int v = (tid < nbs) ? bsum[tid] : 0;
    int a = v;
    s[tid] = a; __syncthreads();
    for (int d = 1; d < SCAN_WG; d <<= 1) {
        int add = (tid >= d) ? s[tid - d] : 0;
        __syncthreads();
        a += add; s[tid] = a;
        __syncthreads();
    }
    if (tid < nbs) bsum[tid] = a - v;
}

__global__ __launch_bounds__(SCAN_WG) void k_scanC(int* __restrict__ tbl,
                                                   const int* __restrict__ bsum, int T) {
    const int i = blockIdx.x * SCAN_WG + threadIdx.x;
    if (i < T) tbl[i] += bsum[blockIdx.x];
}

__global__ __launch_bounds__(THREADS) void k_bmeta(const int* __restrict__ tbl,
                                                   int* __restrict__ boff,
                                                   int* __restrict__ bcnt, int nb, int E) {
    const int b = blockIdx.x * THREADS + threadIdx.x;
    if (b < nb) {
        int s0 = tbl[(size_t)b * NBLK];
        int s1 = (b + 1 < nb) ? tbl[(size_t)(b + 1) * NBLK] : E;
        boff[b] = s0; bcnt[b] = s1 - s0;
    }
}

// ---------------- pass 2: private-offset fill (LDS atomics only) ----------------
__global__ __launch_bounds__(THREADS) void k_fill(const int* __restrict__ src,
                                                  const int* __restrict__ dst,
                                                  const int* __restrict__ tbl,
                                                  int* __restrict__ ebuf,
                                                  int E, int nb, int chunk) {
    __shared__ int wp[NBMAX];
    for (int b = threadIdx.x; b < nb; b += THREADS)
        wp[b] = tbl[b * NBLK + blockIdx.x];
    __syncthreads();
    const int e0 = blockIdx.x * chunk;
    const int e1 = min(E, e0 + chunk);
    for (int e = e0 + threadIdx.x; e < e1; e += THREADS) {
        int s = src[e], d = dst[e];
        int pos = atomicAdd(&wp[d >> BSH], 1);
        ebuf[pos] = (s << BSH) | (d & (BN - 1));
    }
}

// ---------------- bucket -> node-sorted CSR + noff + dinv ----------------
__global__ __launch_bounds__(THREADS) void k_nodesort(const int* __restrict__ ebuf,
                                                      const int* __restrict__ boff,
                                                      const int* __restrict__ bcnt,
                                                      int* __restrict__ csr,
                                                      int* __restrict__ noff,
                                                      float* __restrict__ dinv, int n) {
    __shared__ int hist[BN];
    __shared__ int sc[BN];
    __shared__ int wp[BN];
    const int b = blockIdx.x, t = threadIdx.x;
    const int base = b << BSH;
    const int beg = boff[b], m = bcnt[b];

    if (t < BN) hist[t] = 0;
    __syncthreads();
    for (int j = t; j < m; j += THREADS)
        atomicAdd(&hist[ebuf[beg + j] & (BN - 1)], 1);
    __syncthreads();

    if (t < BN) sc[t] = hist[t];
    __syncthreads();
    for (int d = 1; d < BN; d <<= 1) {
        int add = 0;
        if (t < BN && t >= d) add = sc[t - d];
        __syncthreads();
        if (t < BN) sc[t] += add;
        __syncthreads();
    }
    if (t < BN) {
        int excl = sc[t] - hist[t];
        wp[t] = excl;
        int node = base + t;
        if (node <= n) noff[node] = beg + excl;     // node==n -> noff[n]=E (last bucket)
        if (node < n)  dinv[node] = rsqrtf((float)hist[t] + 1.0f);  // +1 self loop
    }
    __syncthreads();

    for (int j = t; j < m; j += THREADS) {
        int ent = ebuf[beg + j];
        int pos = atomicAdd(&wp[ent & (BN - 1)], 1);
        csr[beg + pos] = ent >> BSH;
    }
}

// ---------------- GEMM1: xw[i][f] = (x[i] @ W1)[f] * dinv[i] ----------------
// 256 threads = 64 node-groups x 4 f-quads; each thread: 4 nodes x 4 feats.
// k staged in 9 slabs of 32; xs chunks XOR-swizzled (c ^= ng&7) so the 16
// distinct node-group reads per wave spread across banks (2-way, free).
__global__ __launch_bounds__(G1_T) void k_gemm1(const float* __restrict__ x,
                                                const float* __restrict__ W1,
                                                const float* __restrict__ dinv,
                                                float* __restrict__ xw, int n) {
    __shared__ float xs[G1_N * G1_KS];      // [row][32], swizzled 16B chunks
    __shared__ float wt[288 * 16];          // raw W1 copy, [k][16]
    const int t = threadIdx.x;
    const int block0 = blockIdx.x * G1_N;

    for (int i = t; i < 288 * 16 / 4; i += G1_T)
        reinterpret_cast<float4*>(wt)[i] = reinterpret_cast<const float4*>(W1)[i];

    const int fq = t & 3;                   // f quad (4 feats)
    const int ng = t >> 2;                  // node group (4 nodes)

    float4 acc0 = {0,0,0,0}, acc1 = {0,0,0,0}, acc2 = {0,0,0,0}, acc3 = {0,0,0,0};

    for (int slab = 0; slab < 9; ++slab) {
        __syncthreads();                    // xs reuse / wt-ready (slab 0)
        // stage 256 rows x 8 chunks (swizzled dest)
        #pragma unroll
        for (int i = 0; i < 8; ++i) {
            int g = i * G1_T + t;           // 0..2047
            int row = g >> 3, c = g & 7;
            int node = block0 + row;
            int csw = c ^ ((row >> 2) & 7);
            float4 v = {0,0,0,0};
            if (node < n)
                v = *reinterpret_cast<const float4*>(&x[(size_t)node * 288 + slab * G1_KS + c * 4]);
            *reinterpret_cast<float4*>(&xs[row * G1_KS + csw * 4]) = v;
        }
        __syncthreads();

        #pragma unroll
        for (int k4 = 0; k4 < 8; ++k4) {
            const int csw = k4 ^ (ng & 7);
            float4 xv0 = *reinterpret_cast<const float4*>(&xs[(ng * 4 + 0) * G1_KS + csw * 4]);
            float4 xv1 = *reinterpret_cast<const float4*>(&xs[(ng * 4 + 1) * G1_KS + csw * 4]);
            float4 xv2 = *reinterpret_cast<const float4*>(&xs[(ng * 4 + 2) * G1_KS + csw * 4]);
            float4 xv3 = *reinterpret_cast<const float4*>(&xs[(ng * 4 + 3) * G1_KS + csw * 4]);
            const int kbase = slab * G1_KS + k4 * 4;
            float4 wv0 = *reinterpret_cast<const float4*>(&wt[(kbase + 0) * 16 + fq * 4]);
            float4 wv1 = *reinterpret_cast<const float4*>(&wt[(kbase + 1) * 16 + fq * 4]);
            float4 wv2 = *reinterpret_cast<const float4*>(&wt[(kbase + 2) * 16 + fq * 4]);
            float4 wv3 = *reinterpret_cast<const float4*>(&wt[(kbase + 3) * 16 + fq * 4]);
            #define G1_FMA(A, XV)                              \
                A.x = fmaf(XV.x, wv0.x, A.x); A.y = fmaf(XV.x, wv0.y, A.y); \
                A.z = fmaf(XV.x, wv0.z, A.z); A.w = fmaf(XV.x, wv0.w, A.w); \
                A.x = fmaf(XV.y, wv1.x, A.x); A.y = fmaf(XV.y, wv1.y, A.y); \
                A.z = fmaf(XV.y, wv1.z, A.z); A.w = fmaf(XV.y, wv1.w, A.w); \
                A.x = fmaf(XV.z, wv2.x, A.x); A.y = fmaf(XV.z, wv2.y, A.y); \
                A.z = fmaf(XV.z, wv2.z, A.z); A.w = fmaf(XV.z, wv2.w, A.w); \
                A.x = fmaf(XV.w, wv3.x, A.x); A.y = fmaf(XV.w, wv3.y, A.y); \
                A.z = fmaf(XV.w, wv3.z, A.z); A.w = fmaf(XV.w, wv3.w, A.w);
            G1_FMA(acc0, xv0)
            G1_FMA(acc1, xv1)
            G1_FMA(acc2, xv2)
            G1_FMA(acc3, xv3)
            #undef G1_FMA
        }
    }

    #pragma unroll
    for (int m = 0; m < 4; ++m) {
        int node = block0 + ng * 4 + m;
        if (node < n) {
            float dv = dinv[node];
            float4 a = (m == 0) ? acc0 : (m == 1) ? acc1 : (m == 2) ? acc2 : acc3;
            a.x *= dv; a.y *= dv; a.z *= dv; a.w *= dv;
            *reinterpret_cast<float4*>(&xw[(size_t)node * 16 + fq * 4]) = a;
        }
    }
}

// ---------------- pull aggregation, F=16, register accumulate ----------------
// 4 lanes per node, each owns one float4 of the row. Input rows pre-scaled
// by dinv[src]; self-loop = own row; epilogue applies dinv[node].
template <int EPI>
__global__ __launch_bounds__(THREADS) void k_pull16(const float* __restrict__ xws,
                                                    const int* __restrict__ csr,
                                                    const int* __restrict__ noff,
                                                    const float* __restrict__ dinv,
                                                    const float* __restrict__ bias,
                                                    float* __restrict__ out, int n) {
    const int t = blockIdx.x * THREADS + threadIdx.x;
    const int node = t >> 2, q = t & 3;
    if (node >= n) return;
    const float4* x4 = reinterpret_cast<const float4*>(xws);
    float4 acc = x4[(size_t)node * 4 + q];          // self loop
    const int beg = noff[node], end = noff[node + 1];
    #pragma unroll 4
    for (int j = beg; j < end; ++j) {
        int s = csr[j];
        float4 v = x4[(size_t)s * 4 + q];
        acc.x += v.x; acc.y += v.y; acc.z += v.z; acc.w += v.w;
    }
    const float dv = dinv[node];
    if (EPI) {
        float4 bb = reinterpret_cast<const float4*>(bias)[q];
        acc.x = fmaxf(fmaf(acc.x, dv, bb.x), 0.f) * dv;
        acc.y = fmaxf(fmaf(acc.y, dv, bb.y), 0.f) * dv;
        acc.z = fmaxf(fmaf(acc.z, dv, bb.z), 0.f) * dv;
        acc.w = fmaxf(fmaf(acc.w, dv, bb.w), 0.f) * dv;
    } else {
        acc.x *= dv; acc.y *= dv; acc.z *= dv; acc.w *= dv;
    }
    reinterpret_cast<float4*>(out)[(size_t)node * 4 + q] = acc;
}

// ---------------- fused head: out = relu(s2 @ W2 + b2) @ Wfc + bfc ----------------
__global__ __launch_bounds__(THREADS) void k_head(const float* __restrict__ s2,
                                                  const float* __restrict__ W2,
                                                  const float* __restrict__ b2,
                                                  const float* __restrict__ Wfc,
                                                  const float* __restrict__ bfc,
                                                  float* __restrict__ out, int n) {
    __shared__ float w2[16 * 32];
    __shared__ float wf[32 * 7];
    __shared__ float bb2[32];
    __shared__ float bbf[7];
    const int t = threadIdx.x;
    for (int i = t; i < 16 * 32; i += THREADS) w2[i] = W2[i];
    for (int i = t; i < 32 * 7; i += THREADS) wf[i] = Wfc[i];
    if (t < 32) bb2[t] = b2[t];
    if (t < 7)  bbf[t] = bfc[t];
    __syncthreads();

    const int i = blockIdx.x * THREADS + t;
    if (i >= n) return;

    float v[16];
    const float4* p = reinterpret_cast<const float4*>(s2 + (size_t)i * 16);
    #pragma unroll
    for (int q = 0; q < 4; ++q) {
        float4 x4 = p[q];
        v[q * 4 + 0] = x4.x; v[q * 4 + 1] = x4.y; v[q * 4 + 2] = x4.z; v[q * 4 + 3] = x4.w;
    }
    float h[32];
    #pragma unroll
    for (int o = 0; o < 32; ++o) {
        float a = bb2[o];
        #pragma unroll
        for (int k = 0; k < 16; ++k) a = fmaf(v[k], w2[k * 32 + o], a);
        h[o] = fmaxf(a, 0.f);
    }
    #pragma unroll
    for (int o = 0; o < 7; ++o) {
        float a = bbf[o];
        #pragma unroll
        for (int k = 0; k < 32; ++k) a = fmaf(h[k], wf[k * 7 + o], a);
        out[(size_t)i * 7 + o] = a;
    }
}

extern "C" void kernel_launch(void* const* d_in, const int* in_sizes, int n_in,
                              void* d_out, int out_size, void* d_ws, size_t ws_size,
                              hipStream_t stream) {
    const float* x   = (const float*)d_in[0];
    const int*   ei  = (const int*)d_in[1];
    const float* W1  = (const float*)d_in[2];
    const float* b1  = (const float*)d_in[3];
    const float* W2  = (const float*)d_in[4];
    const float* b2  = (const float*)d_in[5];
    const float* Wfc = (const float*)d_in[6];
    const float* bfc = (const float*)d_in[7];

    const int n = in_sizes[0] / 288;       // 100000
    const int E = in_sizes[1] / 2;         // 3200000
    const int* src = ei;
    const int* dst = ei + E;
    const int nb = (n + BN - 1) >> BSH;    // 782
    const int T  = nb * NBLK;              // 400384
    const int chunk = (E + NBLK - 1) / NBLK;
    const int nScan = (T + SCAN_WG - 1) / SCAN_WG;   // 391

    int*   wsI  = (int*)d_ws;
    size_t p = 0;
    int*   tbl  = wsI + p;  p += ((size_t)T + 4) & ~(size_t)3;
    int*   bsum = wsI + p;  p += SCAN_WG;
    int*   boff = wsI + p;  p += NBMAX;
    int*   bcnt = wsI + p;  p += NBMAX;
    int*   ebuf = wsI + p;  p += ((size_t)E + 4) & ~(size_t)3;
    int*   csr  = wsI + p;  p += ((size_t)E + 4) & ~(size_t)3;
    int*   noff = wsI + p;  p += ((size_t)n + 8) & ~(size_t)3;
    float* dinv = (float*)(wsI + p);  p += ((size_t)n + 4) & ~(size_t)3;
    float* buf1 = (float*)(wsI + p);  p += (size_t)n * 16;   // xw / s2
    float* buf2 = (float*)(wsI + p);                          // h1
    float* out  = (float*)d_out;

    k_hist <<<NBLK, THREADS, 0, stream>>>(dst, tbl, E, nb, chunk);
    k_scanA<<<nScan, SCAN_WG, 0, stream>>>(tbl, bsum, T);
    k_scanB<<<1, SCAN_WG, 0, stream>>>(bsum, nScan);
    k_scanC<<<nScan, SCAN_WG, 0, stream>>>(tbl, bsum, T);
    k_bmeta<<<(nb + THREADS - 1) / THREADS, THREADS, 0, stream>>>(tbl, boff, bcnt, nb, E);
    k_fill <<<NBLK, THREADS, 0, stream>>>(src, dst, tbl, ebuf, E, nb, chunk);

    k_nodesort<<<nb, THREADS, 0, stream>>>(ebuf, boff, bcnt, csr, noff, dinv, n);

    k_gemm1<<<(n + G1_N - 1) / G1_N, G1_T, 0, stream>>>(x, W1, dinv, buf1, n);

    // layer-1 aggregation + fused relu/bias epilogue (pre-scaled for layer 2)
    k_pull16<1><<<((size_t)n * 4 + THREADS - 1) / THREADS, THREADS, 0, stream>>>(
        buf1, csr, noff, dinv, b1, buf2, n);

    // layer-2 aggregation on 16-wide h1 (aggregate-before-transform)
    k_pull16<0><<<((size_t)n * 4 + THREADS - 1) / THREADS, THREADS, 0, stream>>>(
        buf2, csr, noff, dinv, nullptr, buf1, n);

    // fused: relu(s2 @ W2 + b2) @ Wfc + bfc
    k_head <<<(n + THREADS - 1) / THREADS, THREADS, 0, stream>>>(
        buf1, W2, b2, Wfc, bfc, out, n);
}